// Round 3
// baseline (400.607 us; speedup 1.0000x reference)
//
#include <hip/hip_runtime.h>
#include <hip/hip_bf16.h>
#include <stdint.h>

// Problem: B=8, T=4096, C=1024, D=128 single-head causal attention, fp32 in/out.
// Pipeline: prep_w (W->bf16, transposed) ; qkv_gemm (x@W -> Q,K row-major bf16, V
// transposed bf16) ; attn_fwd (flash attention, bf16 MFMA, fp32 out).

typedef __attribute__((ext_vector_type(8))) short short8;   // 8 bf16 (4 VGPRs)
typedef __attribute__((ext_vector_type(4))) float f32x4;
typedef __attribute__((ext_vector_type(4))) unsigned short u16x4;

#define NB 8
#define NT 4096
#define NC 1024
#define ND 128

__device__ __forceinline__ unsigned short f2bf(float f) {
    union { float f; uint32_t u; } v; v.f = f;
    uint32_t u = v.u;
    return (unsigned short)((u + 0x7FFFu + ((u >> 16) & 1u)) >> 16);  // RNE
}

// ---------------- W -> bf16, transposed: Wbt[w][n][k] = W_w[k][n] ----------------
__global__ void prep_w(const float* __restrict__ Wq, const float* __restrict__ Wk,
                       const float* __restrict__ Wv, unsigned short* __restrict__ Wbt) {
    int idx = blockIdx.x * 256 + threadIdx.x;          // 0 .. 3*128*1024-1
    int w = idx >> 17;                                  // 131072 per matrix
    int rem = idx & 131071;
    int n = rem >> 10;
    int k = rem & 1023;
    const float* W = (w == 0) ? Wq : (w == 1) ? Wk : Wv;
    Wbt[idx] = f2bf(W[k * ND + n]);
}

// ---------------- QKV projection: x[32768][1024] @ W -> bf16 ----------------
// grid (256, 3): blockIdx.x = M-tile (128 rows), blockIdx.y = {Q,K,V}
__global__ __launch_bounds__(256, 2)
void qkv_gemm(const float* __restrict__ x, const unsigned short* __restrict__ Wbt,
              unsigned short* __restrict__ Qo, unsigned short* __restrict__ Ko,
              unsigned short* __restrict__ Vto) {
    __shared__ __align__(16) unsigned short xl[128][40];   // 32 + 8 pad (bf16)
    const int mt = blockIdx.x, nt = blockIdx.y;
    const int tid = threadIdx.x;
    const int lane = tid & 63;
    const int w = tid >> 6;
    const int wr = w >> 1, wc = w & 1;
    const int l15 = lane & 15, lg = lane >> 4;
    const int m0 = mt * 128;
    const unsigned short* Wn = Wbt + (size_t)nt * (ND * NC);

    f32x4 acc[4][4];
#pragma unroll
    for (int i = 0; i < 4; ++i)
#pragma unroll
        for (int j = 0; j < 4; ++j) acc[i][j] = (f32x4)0.0f;

    for (int ks = 0; ks < 32; ++ks) {
        const int k0 = ks * 32;
        // stage x tile (128 x 32 fp32) -> bf16 LDS
#pragma unroll
        for (int i = 0; i < 4; ++i) {
            int f = tid + 256 * i;
            int row = f >> 3, c4 = (f & 7) * 4;
            f32x4 v = *reinterpret_cast<const f32x4*>(&x[(size_t)(m0 + row) * NC + k0 + c4]);
            u16x4 bv;
#pragma unroll
            for (int e = 0; e < 4; ++e) bv[e] = f2bf(v[e]);
            *reinterpret_cast<u16x4*>(&xl[row][c4]) = bv;
        }
        __syncthreads();
        short8 a[4], bb[4];
#pragma unroll
        for (int mi = 0; mi < 4; ++mi)
            a[mi] = *reinterpret_cast<const short8*>(&xl[wr * 64 + mi * 16 + l15][lg * 8]);
#pragma unroll
        for (int ni = 0; ni < 4; ++ni)
            bb[ni] = *reinterpret_cast<const short8*>(
                &Wn[(size_t)(wc * 64 + ni * 16 + l15) * NC + k0 + lg * 8]);
#pragma unroll
        for (int mi = 0; mi < 4; ++mi)
#pragma unroll
            for (int ni = 0; ni < 4; ++ni)
                acc[mi][ni] = __builtin_amdgcn_mfma_f32_16x16x32_bf16(
                    a[mi], bb[ni], acc[mi][ni], 0, 0, 0);
        __syncthreads();
    }
    // epilogue: C/D layout col=lane&15, row=(lane>>4)*4+reg
#pragma unroll
    for (int mi = 0; mi < 4; ++mi)
#pragma unroll
        for (int ni = 0; ni < 4; ++ni)
#pragma unroll
            for (int r = 0; r < 4; ++r) {
                int row = m0 + wr * 64 + mi * 16 + lg * 4 + r;
                int col = wc * 64 + ni * 16 + l15;
                unsigned short bv = f2bf(acc[mi][ni][r]);
                if (nt == 0) Qo[(size_t)row * ND + col] = bv;
                else if (nt == 1) Ko[(size_t)row * ND + col] = bv;
                else {
                    int bb2 = row >> 12, t = row & 4095;
                    Vto[((size_t)(bb2 * ND + col)) * NT + t] = bv;
                }
            }
}

// ---------------- flash attention, causal ----------------
// 512 blocks x 256 threads; block -> (batch, q-tile of 64 rows); wave -> 16 q rows.
// bid<256: qt=bid>>3 (0..31); bid>=256: qt=63-((bid-256)>>3) -> co-resident pairs
// (c, c+256) sum to constant causal work.
__global__ __launch_bounds__(256, 2)
void attn_fwd(const unsigned short* __restrict__ Q, const unsigned short* __restrict__ K,
              const unsigned short* __restrict__ Vt, float* __restrict__ out) {
    __shared__ __align__(16) unsigned short plds[4][16][72];  // per-wave P, pad 64->72
    const int bid = blockIdx.x;
    int qt, b;
    if (bid < 256) { qt = bid >> 3; b = bid & 7; }
    else           { qt = 63 - ((bid - 256) >> 3); b = bid & 7; }
    const int tid = threadIdx.x;
    const int w = tid >> 6, lane = tid & 63;
    const int l15 = lane & 15, lg = lane >> 4;
    const int qb0 = qt * 64;
    const int qw0 = qb0 + w * 16;

    const float sc = 0.08838834764831845f;     // 1/sqrt(128)
    const float L2E = 1.4426950408889634f;

    // Q fragments (hoisted): A-frag lane l holds Q[m=l&15][k-chunk per l>>4]
    short8 qf[4];
    const size_t qbase = ((size_t)b * NT + qw0 + l15) * ND;
#pragma unroll
    for (int c = 0; c < 4; ++c)
        qf[c] = *reinterpret_cast<const short8*>(&Q[qbase + c * 32 + lg * 8]);

    f32x4 o[8];
#pragma unroll
    for (int jn = 0; jn < 8; ++jn) o[jn] = (f32x4)0.0f;
    float mrow[4], lsum[4];
#pragma unroll
    for (int r = 0; r < 4; ++r) { mrow[r] = -1e30f; lsum[r] = 0.0f; }

    for (int s0 = 0; s0 <= qb0; s0 += 64) {
        // ---- S = Q K^T (16 x 64 per wave) ----
        f32x4 s[4];
#pragma unroll
        for (int j = 0; j < 4; ++j) s[j] = (f32x4)0.0f;
        const unsigned short* Kb = &K[((size_t)b * NT + s0 + l15) * ND];
#pragma unroll
        for (int j = 0; j < 4; ++j)
#pragma unroll
            for (int c = 0; c < 4; ++c) {
                short8 kf = *reinterpret_cast<const short8*>(
                    &Kb[(size_t)j * 16 * ND + c * 32 + lg * 8]);
                s[j] = __builtin_amdgcn_mfma_f32_16x16x32_bf16(qf[c], kf, s[j], 0, 0, 0);
            }

        const bool diag = (s0 + 64 > qw0);     // only the last tile needs masking
        float p[4][4], tmax[4];
#pragma unroll
        for (int r = 0; r < 4; ++r) tmax[r] = -1e30f;
#pragma unroll
        for (int j = 0; j < 4; ++j)
#pragma unroll
            for (int r = 0; r < 4; ++r) {
                float sv = s[j][r] * sc;
                if (diag) {
                    int qrow = qw0 + lg * 4 + r;
                    int scol = s0 + j * 16 + l15;
                    if (scol > qrow) sv = -1e30f;
                }
                p[j][r] = sv;
                tmax[r] = fmaxf(tmax[r], sv);
            }
        // row-max over the 16 lanes sharing rows
#pragma unroll
        for (int r = 0; r < 4; ++r) {
#pragma unroll
            for (int off = 1; off < 16; off <<= 1)
                tmax[r] = fmaxf(tmax[r], __shfl_xor(tmax[r], off, 64));
        }
        float alpha[4], psum[4];
#pragma unroll
        for (int r = 0; r < 4; ++r) {
            float mn = fmaxf(mrow[r], tmax[r]);
            alpha[r] = exp2f((mrow[r] - mn) * L2E);
            mrow[r] = mn;
            psum[r] = 0.0f;
        }
#pragma unroll
        for (int j = 0; j < 4; ++j)
#pragma unroll
            for (int r = 0; r < 4; ++r) {
                float pv = exp2f((p[j][r] - mrow[r]) * L2E);
                p[j][r] = pv;
                psum[r] += pv;
            }
#pragma unroll
        for (int r = 0; r < 4; ++r) {
#pragma unroll
            for (int off = 1; off < 16; off <<= 1)
                psum[r] += __shfl_xor(psum[r], off, 64);
            lsum[r] = lsum[r] * alpha[r] + psum[r];
        }
        // rescale O
#pragma unroll
        for (int jn = 0; jn < 8; ++jn)
#pragma unroll
            for (int r = 0; r < 4; ++r) o[jn][r] *= alpha[r];

        // ---- P -> LDS (D-layout coords), reload as A-frags ----
#pragma unroll
        for (int j = 0; j < 4; ++j)
#pragma unroll
            for (int r = 0; r < 4; ++r)
                plds[w][lg * 4 + r][j * 16 + l15] = f2bf(p[j][r]);
        asm volatile("s_waitcnt lgkmcnt(0)" ::: "memory");
        short8 pa[2];
#pragma unroll
        for (int kc = 0; kc < 2; ++kc)
            pa[kc] = *reinterpret_cast<const short8*>(&plds[w][l15][kc * 32 + lg * 8]);

        // ---- O += P V : B-frag from Vt (contiguous in s) ----
#pragma unroll
        for (int jn = 0; jn < 8; ++jn)
#pragma unroll
            for (int kc = 0; kc < 2; ++kc) {
                short8 vf = *reinterpret_cast<const short8*>(
                    &Vt[((size_t)(b * ND + jn * 16 + l15)) * NT + s0 + kc * 32 + lg * 8]);
                o[jn] = __builtin_amdgcn_mfma_f32_16x16x32_bf16(pa[kc], vf, o[jn], 0, 0, 0);
            }
    }
    // epilogue
    float il[4];
#pragma unroll
    for (int r = 0; r < 4; ++r) il[r] = 1.0f / lsum[r];
#pragma unroll
    for (int jn = 0; jn < 8; ++jn)
#pragma unroll
        for (int r = 0; r < 4; ++r) {
            int row = qw0 + lg * 4 + r;
            int col = jn * 16 + l15;
            out[((size_t)b * NT + row) * ND + col] = o[jn][r] * il[r];
        }
}

extern "C" void kernel_launch(void* const* d_in, const int* in_sizes, int n_in,
                              void* d_out, int out_size, void* d_ws, size_t ws_size,
                              hipStream_t stream) {
    const float* x  = (const float*)d_in[0];
    const float* Wq = (const float*)d_in[1];
    const float* Wk = (const float*)d_in[2];
    const float* Wv = (const float*)d_in[3];
    float* out = (float*)d_out;

    unsigned short* ws  = (unsigned short*)d_ws;
    unsigned short* Wbt = ws;                               // 3*128*1024
    unsigned short* Qb  = Wbt + 3 * ND * NC;                // 8*4096*128
    unsigned short* Kb  = Qb + (size_t)NB * NT * ND;
    unsigned short* Vtb = Kb + (size_t)NB * NT * ND;        // transposed [B][D][T]

    prep_w<<<1536, 256, 0, stream>>>(Wq, Wk, Wv, Wbt);
    qkv_gemm<<<dim3(256, 3), 256, 0, stream>>>(x, Wbt, Qb, Kb, Vtb);
    attn_fwd<<<512, 256, 0, stream>>>(Qb, Kb, Vtb, out);
}

// Round 4
// 399.687 us; speedup vs baseline: 1.0023x; 1.0023x over previous
//
#include <hip/hip_runtime.h>
#include <hip/hip_bf16.h>
#include <stdint.h>

// Problem: B=8, T=4096, C=1024, D=128 single-head causal attention, fp32 in/out.
// Pipeline: prep_w (W->bf16, transposed) ; qkv_gemm (x@W -> Q,K row-major bf16, V
// transposed bf16) ; attn_fwd (flash attention, bf16 MFMA, fp32 out).

typedef __attribute__((ext_vector_type(8))) short short8;   // 8 bf16 (4 VGPRs)
typedef __attribute__((ext_vector_type(4))) float f32x4;
typedef __attribute__((ext_vector_type(4))) unsigned short u16x4;

#define NB 8
#define NT 4096
#define NC 1024
#define ND 128

__device__ __forceinline__ unsigned short f2bf(float f) {
    union { float f; uint32_t u; } v; v.f = f;
    uint32_t u = v.u;
    return (unsigned short)((u + 0x7FFFu + ((u >> 16) & 1u)) >> 16);  // RNE
}

// ---------------- W -> bf16, transposed: Wbt[w][n][k] = W_w[k][n] ----------------
__global__ void prep_w(const float* __restrict__ Wq, const float* __restrict__ Wk,
                       const float* __restrict__ Wv, unsigned short* __restrict__ Wbt) {
    int idx = blockIdx.x * 256 + threadIdx.x;          // 0 .. 3*128*1024-1
    int w = idx >> 17;                                  // 131072 per matrix
    int rem = idx & 131071;
    int n = rem >> 10;
    int k = rem & 1023;
    const float* W = (w == 0) ? Wq : (w == 1) ? Wk : Wv;
    Wbt[idx] = f2bf(W[k * ND + n]);
}

// ---------------- QKV projection: x[32768][1024] @ W -> bf16 ----------------
// grid (256, 3): blockIdx.x = M-tile (128 rows), blockIdx.y = {Q,K,V}
__global__ __launch_bounds__(256, 2)
void qkv_gemm(const float* __restrict__ x, const unsigned short* __restrict__ Wbt,
              unsigned short* __restrict__ Qo, unsigned short* __restrict__ Ko,
              unsigned short* __restrict__ Vto) {
    __shared__ __align__(16) unsigned short xl[128][40];   // 32 + 8 pad (bf16)
    const int mt = blockIdx.x, nt = blockIdx.y;
    const int tid = threadIdx.x;
    const int lane = tid & 63;
    const int w = tid >> 6;
    const int wr = w >> 1, wc = w & 1;
    const int l15 = lane & 15, lg = lane >> 4;
    const int m0 = mt * 128;
    const unsigned short* Wn = Wbt + (size_t)nt * (ND * NC);

    f32x4 acc[4][4];
#pragma unroll
    for (int i = 0; i < 4; ++i)
#pragma unroll
        for (int j = 0; j < 4; ++j) acc[i][j] = (f32x4)0.0f;

    for (int ks = 0; ks < 32; ++ks) {
        const int k0 = ks * 32;
        // stage x tile (128 x 32 fp32) -> bf16 LDS
#pragma unroll
        for (int i = 0; i < 4; ++i) {
            int f = tid + 256 * i;
            int row = f >> 3, c4 = (f & 7) * 4;
            f32x4 v = *reinterpret_cast<const f32x4*>(&x[(size_t)(m0 + row) * NC + k0 + c4]);
            u16x4 bv;
#pragma unroll
            for (int e = 0; e < 4; ++e) bv[e] = f2bf(v[e]);
            *reinterpret_cast<u16x4*>(&xl[row][c4]) = bv;
        }
        __syncthreads();
        short8 a[4], bb[4];
#pragma unroll
        for (int mi = 0; mi < 4; ++mi)
            a[mi] = *reinterpret_cast<const short8*>(&xl[wr * 64 + mi * 16 + l15][lg * 8]);
#pragma unroll
        for (int ni = 0; ni < 4; ++ni)
            bb[ni] = *reinterpret_cast<const short8*>(
                &Wn[(size_t)(wc * 64 + ni * 16 + l15) * NC + k0 + lg * 8]);
#pragma unroll
        for (int mi = 0; mi < 4; ++mi)
#pragma unroll
            for (int ni = 0; ni < 4; ++ni)
                acc[mi][ni] = __builtin_amdgcn_mfma_f32_16x16x32_bf16(
                    a[mi], bb[ni], acc[mi][ni], 0, 0, 0);
        __syncthreads();
    }
    // epilogue: C/D layout col=lane&15, row=(lane>>4)*4+reg
#pragma unroll
    for (int mi = 0; mi < 4; ++mi)
#pragma unroll
        for (int ni = 0; ni < 4; ++ni)
#pragma unroll
            for (int r = 0; r < 4; ++r) {
                int row = m0 + wr * 64 + mi * 16 + lg * 4 + r;
                int col = wc * 64 + ni * 16 + l15;
                unsigned short bv = f2bf(acc[mi][ni][r]);
                if (nt == 0) Qo[(size_t)row * ND + col] = bv;
                else if (nt == 1) Ko[(size_t)row * ND + col] = bv;
                else {
                    int bb2 = row >> 12, t = row & 4095;
                    Vto[((size_t)(bb2 * ND + col)) * NT + t] = bv;
                }
            }
}

// ---------------- flash attention, causal ----------------
// 512 blocks x 256 threads; block -> (batch, q-tile of 64 rows); wave -> 16 q rows.
// bid<256: qt=bid>>3 (0..31); bid>=256: qt=63-((bid-256)>>3) -> co-resident pairs
// (c, c+256) sum to constant causal work.
__global__ __launch_bounds__(256, 2)
void attn_fwd(const unsigned short* __restrict__ Q, const unsigned short* __restrict__ K,
              const unsigned short* __restrict__ Vt, float* __restrict__ out) {
    __shared__ __align__(16) unsigned short plds[4][16][72];  // per-wave P, pad 64->72
    const int bid = blockIdx.x;
    int qt, b;
    if (bid < 256) { qt = bid >> 3; b = bid & 7; }
    else           { qt = 63 - ((bid - 256) >> 3); b = bid & 7; }
    const int tid = threadIdx.x;
    const int w = tid >> 6, lane = tid & 63;
    const int l15 = lane & 15, lg = lane >> 4;
    const int qb0 = qt * 64;
    const int qw0 = qb0 + w * 16;

    const float sc = 0.08838834764831845f;     // 1/sqrt(128)
    const float L2E = 1.4426950408889634f;

    // Q fragments (hoisted): A-frag lane l holds Q[m=l&15][k-chunk per l>>4]
    short8 qf[4];
    const size_t qbase = ((size_t)b * NT + qw0 + l15) * ND;
#pragma unroll
    for (int c = 0; c < 4; ++c)
        qf[c] = *reinterpret_cast<const short8*>(&Q[qbase + c * 32 + lg * 8]);

    f32x4 o[8];
#pragma unroll
    for (int jn = 0; jn < 8; ++jn) o[jn] = (f32x4)0.0f;
    float mrow[4], lsum[4];
#pragma unroll
    for (int r = 0; r < 4; ++r) { mrow[r] = -1e30f; lsum[r] = 0.0f; }

    for (int s0 = 0; s0 <= qb0; s0 += 64) {
        // ---- S = Q K^T (16 x 64 per wave) ----
        f32x4 s[4];
#pragma unroll
        for (int j = 0; j < 4; ++j) s[j] = (f32x4)0.0f;
        const unsigned short* Kb = &K[((size_t)b * NT + s0 + l15) * ND];
#pragma unroll
        for (int j = 0; j < 4; ++j)
#pragma unroll
            for (int c = 0; c < 4; ++c) {
                short8 kf = *reinterpret_cast<const short8*>(
                    &Kb[(size_t)j * 16 * ND + c * 32 + lg * 8]);
                s[j] = __builtin_amdgcn_mfma_f32_16x16x32_bf16(qf[c], kf, s[j], 0, 0, 0);
            }

        const bool diag = (s0 + 64 > qw0);     // only the last tile needs masking
        float p[4][4], tmax[4];
#pragma unroll
        for (int r = 0; r < 4; ++r) tmax[r] = -1e30f;
#pragma unroll
        for (int j = 0; j < 4; ++j)
#pragma unroll
            for (int r = 0; r < 4; ++r) {
                float sv = s[j][r] * sc;
                if (diag) {
                    int qrow = qw0 + lg * 4 + r;
                    int scol = s0 + j * 16 + l15;
                    if (scol > qrow) sv = -1e30f;
                }
                p[j][r] = sv;
                tmax[r] = fmaxf(tmax[r], sv);
            }
        // row-max over the 16 lanes sharing rows
#pragma unroll
        for (int r = 0; r < 4; ++r) {
#pragma unroll
            for (int off = 1; off < 16; off <<= 1)
                tmax[r] = fmaxf(tmax[r], __shfl_xor(tmax[r], off, 64));
        }
        float alpha[4], psum[4];
#pragma unroll
        for (int r = 0; r < 4; ++r) {
            float mn = fmaxf(mrow[r], tmax[r]);
            alpha[r] = exp2f((mrow[r] - mn) * L2E);
            mrow[r] = mn;
            psum[r] = 0.0f;
        }
#pragma unroll
        for (int j = 0; j < 4; ++j)
#pragma unroll
            for (int r = 0; r < 4; ++r) {
                float pv = exp2f((p[j][r] - mrow[r]) * L2E);
                p[j][r] = pv;
                psum[r] += pv;
            }
#pragma unroll
        for (int r = 0; r < 4; ++r) {
#pragma unroll
            for (int off = 1; off < 16; off <<= 1)
                psum[r] += __shfl_xor(psum[r], off, 64);
            lsum[r] = lsum[r] * alpha[r] + psum[r];
        }
        // rescale O
#pragma unroll
        for (int jn = 0; jn < 8; ++jn)
#pragma unroll
            for (int r = 0; r < 4; ++r) o[jn][r] *= alpha[r];

        // ---- P -> LDS (D-layout coords), reload as A-frags ----
#pragma unroll
        for (int j = 0; j < 4; ++j)
#pragma unroll
            for (int r = 0; r < 4; ++r)
                plds[w][lg * 4 + r][j * 16 + l15] = f2bf(p[j][r]);
        asm volatile("s_waitcnt lgkmcnt(0)" ::: "memory");
        short8 pa[2];
#pragma unroll
        for (int kc = 0; kc < 2; ++kc)
            pa[kc] = *reinterpret_cast<const short8*>(&plds[w][l15][kc * 32 + lg * 8]);

        // ---- O += P V : B-frag from Vt (contiguous in s) ----
#pragma unroll
        for (int jn = 0; jn < 8; ++jn)
#pragma unroll
            for (int kc = 0; kc < 2; ++kc) {
                short8 vf = *reinterpret_cast<const short8*>(
                    &Vt[((size_t)(b * ND + jn * 16 + l15)) * NT + s0 + kc * 32 + lg * 8]);
                o[jn] = __builtin_amdgcn_mfma_f32_16x16x32_bf16(pa[kc], vf, o[jn], 0, 0, 0);
            }
    }
    // epilogue
    float il[4];
#pragma unroll
    for (int r = 0; r < 4; ++r) il[r] = 1.0f / lsum[r];
#pragma unroll
    for (int jn = 0; jn < 8; ++jn)
#pragma unroll
        for (int r = 0; r < 4; ++r) {
            int row = qw0 + lg * 4 + r;
            int col = jn * 16 + l15;
            out[((size_t)b * NT + row) * ND + col] = o[jn][r] * il[r];
        }
}

extern "C" void kernel_launch(void* const* d_in, const int* in_sizes, int n_in,
                              void* d_out, int out_size, void* d_ws, size_t ws_size,
                              hipStream_t stream) {
    const float* x  = (const float*)d_in[0];
    const float* Wq = (const float*)d_in[1];
    const float* Wk = (const float*)d_in[2];
    const float* Wv = (const float*)d_in[3];
    float* out = (float*)d_out;

    unsigned short* ws  = (unsigned short*)d_ws;
    unsigned short* Wbt = ws;                               // 3*128*1024
    unsigned short* Qb  = Wbt + 3 * ND * NC;                // 8*4096*128
    unsigned short* Kb  = Qb + (size_t)NB * NT * ND;
    unsigned short* Vtb = Kb + (size_t)NB * NT * ND;        // transposed [B][D][T]

    prep_w<<<1536, 256, 0, stream>>>(Wq, Wk, Wv, Wbt);
    qkv_gemm<<<dim3(256, 3), 256, 0, stream>>>(x, Wbt, Qb, Kb, Vtb);
    attn_fwd<<<512, 256, 0, stream>>>(Qb, Kb, Vtb, out);
}

// Round 5
// 399.498 us; speedup vs baseline: 1.0028x; 1.0005x over previous
//
#include <hip/hip_runtime.h>
#include <hip/hip_bf16.h>
#include <stdint.h>

// Problem: B=8, T=4096, C=1024, D=128 single-head causal attention, fp32 in/out.
// Pipeline: prep_w (W->bf16, transposed) ; qkv_gemm (x@W -> Q,K row-major bf16, V
// transposed bf16) ; attn_fwd (flash attention, bf16 MFMA, fp32 out).

typedef __attribute__((ext_vector_type(8))) short short8;   // 8 bf16 (4 VGPRs)
typedef __attribute__((ext_vector_type(4))) float f32x4;
typedef __attribute__((ext_vector_type(4))) unsigned short u16x4;

#define NB 8
#define NT 4096
#define NC 1024
#define ND 128

__device__ __forceinline__ unsigned short f2bf(float f) {
    union { float f; uint32_t u; } v; v.f = f;
    uint32_t u = v.u;
    return (unsigned short)((u + 0x7FFFu + ((u >> 16) & 1u)) >> 16);  // RNE
}

// ---------------- W -> bf16, transposed: Wbt[w][n][k] = W_w[k][n] ----------------
__global__ void prep_w(const float* __restrict__ Wq, const float* __restrict__ Wk,
                       const float* __restrict__ Wv, unsigned short* __restrict__ Wbt) {
    int idx = blockIdx.x * 256 + threadIdx.x;          // 0 .. 3*128*1024-1
    int w = idx >> 17;                                  // 131072 per matrix
    int rem = idx & 131071;
    int n = rem >> 10;
    int k = rem & 1023;
    const float* W = (w == 0) ? Wq : (w == 1) ? Wk : Wv;
    Wbt[idx] = f2bf(W[k * ND + n]);
}

// ---------------- QKV projection: x[32768][1024] @ W -> bf16 ----------------
// grid (256, 3): blockIdx.x = M-tile (128 rows), blockIdx.y = {Q,K,V}
__global__ __launch_bounds__(256, 2)
void qkv_gemm(const float* __restrict__ x, const unsigned short* __restrict__ Wbt,
              unsigned short* __restrict__ Qo, unsigned short* __restrict__ Ko,
              unsigned short* __restrict__ Vto) {
    __shared__ __align__(16) unsigned short xl[128][40];   // 32 + 8 pad (bf16)
    const int mt = blockIdx.x, nt = blockIdx.y;
    const int tid = threadIdx.x;
    const int lane = tid & 63;
    const int w = tid >> 6;
    const int wr = w >> 1, wc = w & 1;
    const int l15 = lane & 15, lg = lane >> 4;
    const int m0 = mt * 128;
    const unsigned short* Wn = Wbt + (size_t)nt * (ND * NC);

    f32x4 acc[4][4];
#pragma unroll
    for (int i = 0; i < 4; ++i)
#pragma unroll
        for (int j = 0; j < 4; ++j) acc[i][j] = (f32x4)0.0f;

    for (int ks = 0; ks < 32; ++ks) {
        const int k0 = ks * 32;
        // stage x tile (128 x 32 fp32) -> bf16 LDS
#pragma unroll
        for (int i = 0; i < 4; ++i) {
            int f = tid + 256 * i;
            int row = f >> 3, c4 = (f & 7) * 4;
            f32x4 v = *reinterpret_cast<const f32x4*>(&x[(size_t)(m0 + row) * NC + k0 + c4]);
            u16x4 bv;
#pragma unroll
            for (int e = 0; e < 4; ++e) bv[e] = f2bf(v[e]);
            *reinterpret_cast<u16x4*>(&xl[row][c4]) = bv;
        }
        __syncthreads();
        short8 a[4], bb[4];
#pragma unroll
        for (int mi = 0; mi < 4; ++mi)
            a[mi] = *reinterpret_cast<const short8*>(&xl[wr * 64 + mi * 16 + l15][lg * 8]);
#pragma unroll
        for (int ni = 0; ni < 4; ++ni)
            bb[ni] = *reinterpret_cast<const short8*>(
                &Wn[(size_t)(wc * 64 + ni * 16 + l15) * NC + k0 + lg * 8]);
#pragma unroll
        for (int mi = 0; mi < 4; ++mi)
#pragma unroll
            for (int ni = 0; ni < 4; ++ni)
                acc[mi][ni] = __builtin_amdgcn_mfma_f32_16x16x32_bf16(
                    a[mi], bb[ni], acc[mi][ni], 0, 0, 0);
        __syncthreads();
    }
    // epilogue: C/D layout col=lane&15, row=(lane>>4)*4+reg
#pragma unroll
    for (int mi = 0; mi < 4; ++mi)
#pragma unroll
        for (int ni = 0; ni < 4; ++ni)
#pragma unroll
            for (int r = 0; r < 4; ++r) {
                int row = m0 + wr * 64 + mi * 16 + lg * 4 + r;
                int col = wc * 64 + ni * 16 + l15;
                unsigned short bv = f2bf(acc[mi][ni][r]);
                if (nt == 0) Qo[(size_t)row * ND + col] = bv;
                else if (nt == 1) Ko[(size_t)row * ND + col] = bv;
                else {
                    int bb2 = row >> 12, t = row & 4095;
                    Vto[((size_t)(bb2 * ND + col)) * NT + t] = bv;
                }
            }
}

// ---------------- flash attention, causal ----------------
// 512 blocks x 256 threads; block -> (batch, q-tile of 64 rows); wave -> 16 q rows.
// bid<256: qt=bid>>3 (0..31); bid>=256: qt=63-((bid-256)>>3) -> co-resident pairs
// (c, c+256) sum to constant causal work.
__global__ __launch_bounds__(256, 2)
void attn_fwd(const unsigned short* __restrict__ Q, const unsigned short* __restrict__ K,
              const unsigned short* __restrict__ Vt, float* __restrict__ out) {
    __shared__ __align__(16) unsigned short plds[4][16][72];  // per-wave P, pad 64->72
    const int bid = blockIdx.x;
    int qt, b;
    if (bid < 256) { qt = bid >> 3; b = bid & 7; }
    else           { qt = 63 - ((bid - 256) >> 3); b = bid & 7; }
    const int tid = threadIdx.x;
    const int w = tid >> 6, lane = tid & 63;
    const int l15 = lane & 15, lg = lane >> 4;
    const int qb0 = qt * 64;
    const int qw0 = qb0 + w * 16;

    const float sc = 0.08838834764831845f;     // 1/sqrt(128)
    const float L2E = 1.4426950408889634f;

    // Q fragments (hoisted): A-frag lane l holds Q[m=l&15][k-chunk per l>>4]
    short8 qf[4];
    const size_t qbase = ((size_t)b * NT + qw0 + l15) * ND;
#pragma unroll
    for (int c = 0; c < 4; ++c)
        qf[c] = *reinterpret_cast<const short8*>(&Q[qbase + c * 32 + lg * 8]);

    f32x4 o[8];
#pragma unroll
    for (int jn = 0; jn < 8; ++jn) o[jn] = (f32x4)0.0f;
    float mrow[4], lsum[4];
#pragma unroll
    for (int r = 0; r < 4; ++r) { mrow[r] = -1e30f; lsum[r] = 0.0f; }

    for (int s0 = 0; s0 <= qb0; s0 += 64) {
        // ---- S = Q K^T (16 x 64 per wave) ----
        f32x4 s[4];
#pragma unroll
        for (int j = 0; j < 4; ++j) s[j] = (f32x4)0.0f;
        const unsigned short* Kb = &K[((size_t)b * NT + s0 + l15) * ND];
#pragma unroll
        for (int j = 0; j < 4; ++j)
#pragma unroll
            for (int c = 0; c < 4; ++c) {
                short8 kf = *reinterpret_cast<const short8*>(
                    &Kb[(size_t)j * 16 * ND + c * 32 + lg * 8]);
                s[j] = __builtin_amdgcn_mfma_f32_16x16x32_bf16(qf[c], kf, s[j], 0, 0, 0);
            }

        const bool diag = (s0 + 64 > qw0);     // only the last tile needs masking
        float p[4][4], tmax[4];
#pragma unroll
        for (int r = 0; r < 4; ++r) tmax[r] = -1e30f;
#pragma unroll
        for (int j = 0; j < 4; ++j)
#pragma unroll
            for (int r = 0; r < 4; ++r) {
                float sv = s[j][r] * sc;
                if (diag) {
                    int qrow = qw0 + lg * 4 + r;
                    int scol = s0 + j * 16 + l15;
                    if (scol > qrow) sv = -1e30f;
                }
                p[j][r] = sv;
                tmax[r] = fmaxf(tmax[r], sv);
            }
        // row-max over the 16 lanes sharing rows
#pragma unroll
        for (int r = 0; r < 4; ++r) {
#pragma unroll
            for (int off = 1; off < 16; off <<= 1)
                tmax[r] = fmaxf(tmax[r], __shfl_xor(tmax[r], off, 64));
        }
        float alpha[4], psum[4];
#pragma unroll
        for (int r = 0; r < 4; ++r) {
            float mn = fmaxf(mrow[r], tmax[r]);
            alpha[r] = exp2f((mrow[r] - mn) * L2E);
            mrow[r] = mn;
            psum[r] = 0.0f;
        }
#pragma unroll
        for (int j = 0; j < 4; ++j)
#pragma unroll
            for (int r = 0; r < 4; ++r) {
                float pv = exp2f((p[j][r] - mrow[r]) * L2E);
                p[j][r] = pv;
                psum[r] += pv;
            }
#pragma unroll
        for (int r = 0; r < 4; ++r) {
#pragma unroll
            for (int off = 1; off < 16; off <<= 1)
                psum[r] += __shfl_xor(psum[r], off, 64);
            lsum[r] = lsum[r] * alpha[r] + psum[r];
        }
        // rescale O
#pragma unroll
        for (int jn = 0; jn < 8; ++jn)
#pragma unroll
            for (int r = 0; r < 4; ++r) o[jn][r] *= alpha[r];

        // ---- P -> LDS (D-layout coords), reload as A-frags ----
#pragma unroll
        for (int j = 0; j < 4; ++j)
#pragma unroll
            for (int r = 0; r < 4; ++r)
                plds[w][lg * 4 + r][j * 16 + l15] = f2bf(p[j][r]);
        asm volatile("s_waitcnt lgkmcnt(0)" ::: "memory");
        short8 pa[2];
#pragma unroll
        for (int kc = 0; kc < 2; ++kc)
            pa[kc] = *reinterpret_cast<const short8*>(&plds[w][l15][kc * 32 + lg * 8]);

        // ---- O += P V : B-frag from Vt (contiguous in s) ----
#pragma unroll
        for (int jn = 0; jn < 8; ++jn)
#pragma unroll
            for (int kc = 0; kc < 2; ++kc) {
                short8 vf = *reinterpret_cast<const short8*>(
                    &Vt[((size_t)(b * ND + jn * 16 + l15)) * NT + s0 + kc * 32 + lg * 8]);
                o[jn] = __builtin_amdgcn_mfma_f32_16x16x32_bf16(pa[kc], vf, o[jn], 0, 0, 0);
            }
    }
    // epilogue
    float il[4];
#pragma unroll
    for (int r = 0; r < 4; ++r) il[r] = 1.0f / lsum[r];
#pragma unroll
    for (int jn = 0; jn < 8; ++jn)
#pragma unroll
        for (int r = 0; r < 4; ++r) {
            int row = qw0 + lg * 4 + r;
            int col = jn * 16 + l15;
            out[((size_t)b * NT + row) * ND + col] = o[jn][r] * il[r];
        }
}

extern "C" void kernel_launch(void* const* d_in, const int* in_sizes, int n_in,
                              void* d_out, int out_size, void* d_ws, size_t ws_size,
                              hipStream_t stream) {
    const float* x  = (const float*)d_in[0];
    const float* Wq = (const float*)d_in[1];
    const float* Wk = (const float*)d_in[2];
    const float* Wv = (const float*)d_in[3];
    float* out = (float*)d_out;

    unsigned short* ws  = (unsigned short*)d_ws;
    unsigned short* Wbt = ws;                               // 3*128*1024
    unsigned short* Qb  = Wbt + 3 * ND * NC;                // 8*4096*128
    unsigned short* Kb  = Qb + (size_t)NB * NT * ND;
    unsigned short* Vtb = Kb + (size_t)NB * NT * ND;        // transposed [B][D][T]

    prep_w<<<1536, 256, 0, stream>>>(Wq, Wk, Wv, Wbt);
    qkv_gemm<<<dim3(256, 3), 256, 0, stream>>>(x, Wbt, Qb, Kb, Vtb);
    attn_fwd<<<512, 256, 0, stream>>>(Qb, Kb, Vtb, out);
}

// Round 6
// 356.433 us; speedup vs baseline: 1.1239x; 1.1208x over previous
//
#include <hip/hip_runtime.h>
#include <hip/hip_bf16.h>
#include <stdint.h>

// Problem: B=8, T=4096, C=1024, D=128 single-head causal attention, fp32 in/out.
// Pipeline: prep_w (W->bf16, transposed) ; qkv_gemm (x@W -> Q,K row-major bf16, V
// transposed bf16) ; attn_fwd (flash attention, bf16 MFMA, fp32 out).
// R5: split-KV x2 (1024 blocks, 16 waves/CU), V-prefetch under softmax, setprio.

typedef __attribute__((ext_vector_type(8))) short short8;   // 8 bf16 (4 VGPRs)
typedef __attribute__((ext_vector_type(4))) float f32x4;
typedef __attribute__((ext_vector_type(4))) unsigned short u16x4;

#define NB 8
#define NT 4096
#define NC 1024
#define ND 128

__device__ __forceinline__ unsigned short f2bf(float f) {
    union { float f; uint32_t u; } v; v.f = f;
    uint32_t u = v.u;
    return (unsigned short)((u + 0x7FFFu + ((u >> 16) & 1u)) >> 16);  // RNE
}

// ---------------- W -> bf16, transposed: Wbt[w][n][k] = W_w[k][n] ----------------
__global__ void prep_w(const float* __restrict__ Wq, const float* __restrict__ Wk,
                       const float* __restrict__ Wv, unsigned short* __restrict__ Wbt) {
    int idx = blockIdx.x * 256 + threadIdx.x;          // 0 .. 3*128*1024-1
    int w = idx >> 17;                                  // 131072 per matrix
    int rem = idx & 131071;
    int n = rem >> 10;
    int k = rem & 1023;
    const float* W = (w == 0) ? Wq : (w == 1) ? Wk : Wv;
    Wbt[idx] = f2bf(W[k * ND + n]);
}

// ---------------- QKV projection: x[32768][1024] @ W -> bf16 ----------------
// grid (256, 3): blockIdx.x = M-tile (128 rows), blockIdx.y = {Q,K,V}
__global__ __launch_bounds__(256, 2)
void qkv_gemm(const float* __restrict__ x, const unsigned short* __restrict__ Wbt,
              unsigned short* __restrict__ Qo, unsigned short* __restrict__ Ko,
              unsigned short* __restrict__ Vto) {
    __shared__ __align__(16) unsigned short xl[128][40];   // 32 + 8 pad (bf16)
    const int mt = blockIdx.x, nt = blockIdx.y;
    const int tid = threadIdx.x;
    const int lane = tid & 63;
    const int w = tid >> 6;
    const int wr = w >> 1, wc = w & 1;
    const int l15 = lane & 15, lg = lane >> 4;
    const int m0 = mt * 128;
    const unsigned short* Wn = Wbt + (size_t)nt * (ND * NC);

    f32x4 acc[4][4];
#pragma unroll
    for (int i = 0; i < 4; ++i)
#pragma unroll
        for (int j = 0; j < 4; ++j) acc[i][j] = (f32x4)0.0f;

    for (int ks = 0; ks < 32; ++ks) {
        const int k0 = ks * 32;
        // stage x tile (128 x 32 fp32) -> bf16 LDS
#pragma unroll
        for (int i = 0; i < 4; ++i) {
            int f = tid + 256 * i;
            int row = f >> 3, c4 = (f & 7) * 4;
            f32x4 v = *reinterpret_cast<const f32x4*>(&x[(size_t)(m0 + row) * NC + k0 + c4]);
            u16x4 bv;
#pragma unroll
            for (int e = 0; e < 4; ++e) bv[e] = f2bf(v[e]);
            *reinterpret_cast<u16x4*>(&xl[row][c4]) = bv;
        }
        __syncthreads();
        short8 a[4], bb[4];
#pragma unroll
        for (int mi = 0; mi < 4; ++mi)
            a[mi] = *reinterpret_cast<const short8*>(&xl[wr * 64 + mi * 16 + l15][lg * 8]);
#pragma unroll
        for (int ni = 0; ni < 4; ++ni)
            bb[ni] = *reinterpret_cast<const short8*>(
                &Wn[(size_t)(wc * 64 + ni * 16 + l15) * NC + k0 + lg * 8]);
#pragma unroll
        for (int mi = 0; mi < 4; ++mi)
#pragma unroll
            for (int ni = 0; ni < 4; ++ni)
                acc[mi][ni] = __builtin_amdgcn_mfma_f32_16x16x32_bf16(
                    a[mi], bb[ni], acc[mi][ni], 0, 0, 0);
        __syncthreads();
    }
    // epilogue: C/D layout col=lane&15, row=(lane>>4)*4+reg
#pragma unroll
    for (int mi = 0; mi < 4; ++mi)
#pragma unroll
        for (int ni = 0; ni < 4; ++ni)
#pragma unroll
            for (int r = 0; r < 4; ++r) {
                int row = m0 + wr * 64 + mi * 16 + lg * 4 + r;
                int col = wc * 64 + ni * 16 + l15;
                unsigned short bv = f2bf(acc[mi][ni][r]);
                if (nt == 0) Qo[(size_t)row * ND + col] = bv;
                else if (nt == 1) Ko[(size_t)row * ND + col] = bv;
                else {
                    int bb2 = row >> 12, t = row & 4095;
                    Vto[((size_t)(bb2 * ND + col)) * NT + t] = bv;
                }
            }
}

// ---------------- flash attention, causal, split-KV x2 ----------------
// 1024 blocks x 256 threads; block -> (batch, 32-row q tile).
// wave w: wq = w&1 (16-row q chunk), wk = w>>1 (KV tile parity).
// Waves (wk=0) do s0 = 0,128,256,...; waves (wk=1) do s0 = 64,192,...
// Each keeps its own (m,l,O); merged through LDS at the end.
// Causal balance: bid<512 -> qt = bid>>3 (0..63); else qt = 127-((bid-512)>>3).
__global__ __launch_bounds__(256, 4)
void attn_fwd(const unsigned short* __restrict__ Q, const unsigned short* __restrict__ K,
              const unsigned short* __restrict__ Vt, float* __restrict__ out) {
    __shared__ __align__(16) unsigned short plds[4][16][72];  // per-wave P buffer
    __shared__ __align__(16) float oBl[2][16][132];           // wk=1 partial O (pad 132)
    __shared__ float mlB[2][2][16];                            // wk=1 partial m,l

    const int bid = blockIdx.x;
    int qt, b;
    if (bid < 512) { qt = bid >> 3; b = bid & 7; }
    else           { qt = 127 - ((bid - 512) >> 3); b = bid & 7; }
    const int tid = threadIdx.x;
    const int w = tid >> 6, lane = tid & 63;
    const int l15 = lane & 15, lg = lane >> 4;
    const int wq = w & 1;        // q sub-tile within the 32-row block tile
    const int wk = w >> 1;       // KV tile parity
    const int qb0 = qt * 32;
    const int qw0 = qb0 + wq * 16;
    const int s0max = (qb0 >> 6) << 6;   // last 64-wide KV tile index

    const float sc = 0.08838834764831845f;     // 1/sqrt(128)
    const float L2E = 1.4426950408889634f;

    // Q fragments (hoisted): A-frag lane l holds Q[m=l&15][k-chunk per l>>4]
    short8 qf[4];
    const size_t qbase = ((size_t)b * NT + qw0 + l15) * ND;
#pragma unroll
    for (int c = 0; c < 4; ++c)
        qf[c] = *reinterpret_cast<const short8*>(&Q[qbase + c * 32 + lg * 8]);

    f32x4 o[8];
#pragma unroll
    for (int jn = 0; jn < 8; ++jn) o[jn] = (f32x4)0.0f;
    float mrow[4], lsum[4];
#pragma unroll
    for (int r = 0; r < 4; ++r) { mrow[r] = -1e30f; lsum[r] = 0.0f; }

    const unsigned short* Kbase = &K[(size_t)b * NT * ND];
    const unsigned short* Vbase = &Vt[(size_t)b * ND * NT];

    for (int s0 = wk * 64; s0 <= s0max; s0 += 128) {
        // ---- S = Q K^T (16 x 64 per wave); reuse s[] as p[] after scaling ----
        f32x4 s[4];
#pragma unroll
        for (int j = 0; j < 4; ++j) s[j] = (f32x4)0.0f;
        const unsigned short* Kb = Kbase + ((size_t)(s0 + l15)) * ND;
        __builtin_amdgcn_s_setprio(1);
#pragma unroll
        for (int j = 0; j < 4; ++j)
#pragma unroll
            for (int c = 0; c < 4; ++c) {
                short8 kf = *reinterpret_cast<const short8*>(
                    &Kb[(size_t)j * 16 * ND + c * 32 + lg * 8]);
                s[j] = __builtin_amdgcn_mfma_f32_16x16x32_bf16(qf[c], kf, s[j], 0, 0, 0);
            }
        __builtin_amdgcn_s_setprio(0);

        // ---- prefetch V half (jn=0..3): latency hides under softmax ----
        short8 vf0[8];
#pragma unroll
        for (int jn = 0; jn < 4; ++jn)
#pragma unroll
            for (int kc = 0; kc < 2; ++kc)
                vf0[jn * 2 + kc] = *reinterpret_cast<const short8*>(
                    &Vbase[((size_t)(jn * 16 + l15)) * NT + s0 + kc * 32 + lg * 8]);

        // ---- softmax (online) ----
        const bool diag = (s0 + 64 > qw0);
        float tmax[4];
#pragma unroll
        for (int r = 0; r < 4; ++r) tmax[r] = -1e30f;
#pragma unroll
        for (int j = 0; j < 4; ++j)
#pragma unroll
            for (int r = 0; r < 4; ++r) {
                float sv = s[j][r] * sc;
                if (diag) {
                    int qrow = qw0 + lg * 4 + r;
                    int scol = s0 + j * 16 + l15;
                    if (scol > qrow) sv = -1e30f;
                }
                s[j][r] = sv;
                tmax[r] = fmaxf(tmax[r], sv);
            }
#pragma unroll
        for (int r = 0; r < 4; ++r) {
#pragma unroll
            for (int off = 1; off < 16; off <<= 1)
                tmax[r] = fmaxf(tmax[r], __shfl_xor(tmax[r], off, 64));
        }
        float alpha[4], psum[4];
#pragma unroll
        for (int r = 0; r < 4; ++r) {
            float mn = fmaxf(mrow[r], tmax[r]);
            alpha[r] = exp2f((mrow[r] - mn) * L2E);
            mrow[r] = mn;
            psum[r] = 0.0f;
        }
#pragma unroll
        for (int j = 0; j < 4; ++j)
#pragma unroll
            for (int r = 0; r < 4; ++r) {
                float pv = exp2f((s[j][r] - mrow[r]) * L2E);
                s[j][r] = pv;
                psum[r] += pv;
            }
#pragma unroll
        for (int r = 0; r < 4; ++r) {
#pragma unroll
            for (int off = 1; off < 16; off <<= 1)
                psum[r] += __shfl_xor(psum[r], off, 64);
            lsum[r] = lsum[r] * alpha[r] + psum[r];
        }
        // rescale O
#pragma unroll
        for (int jn = 0; jn < 8; ++jn)
#pragma unroll
            for (int r = 0; r < 4; ++r) o[jn][r] *= alpha[r];

        // ---- P -> LDS (D-layout coords), reload as A-frags ----
#pragma unroll
        for (int j = 0; j < 4; ++j)
#pragma unroll
            for (int r = 0; r < 4; ++r)
                plds[w][lg * 4 + r][j * 16 + l15] = f2bf(s[j][r]);
        asm volatile("s_waitcnt lgkmcnt(0)" ::: "memory");
        short8 pa[2];
#pragma unroll
        for (int kc = 0; kc < 2; ++kc)
            pa[kc] = *reinterpret_cast<const short8*>(&plds[w][l15][kc * 32 + lg * 8]);

        // ---- O += P V : half 0 from prefetched regs, half 1 inline ----
        __builtin_amdgcn_s_setprio(1);
#pragma unroll
        for (int jn = 0; jn < 4; ++jn)
#pragma unroll
            for (int kc = 0; kc < 2; ++kc)
                o[jn] = __builtin_amdgcn_mfma_f32_16x16x32_bf16(
                    pa[kc], vf0[jn * 2 + kc], o[jn], 0, 0, 0);
#pragma unroll
        for (int jn = 4; jn < 8; ++jn)
#pragma unroll
            for (int kc = 0; kc < 2; ++kc) {
                short8 vf = *reinterpret_cast<const short8*>(
                    &Vbase[((size_t)(jn * 16 + l15)) * NT + s0 + kc * 32 + lg * 8]);
                o[jn] = __builtin_amdgcn_mfma_f32_16x16x32_bf16(pa[kc], vf, o[jn], 0, 0, 0);
            }
        __builtin_amdgcn_s_setprio(0);
    }

    // ---- merge wk=1 partials into wk=0, write out ----
    if (wk == 1) {
#pragma unroll
        for (int jn = 0; jn < 8; ++jn)
#pragma unroll
            for (int r = 0; r < 4; ++r)
                oBl[wq][lg * 4 + r][jn * 16 + l15] = o[jn][r];
        if (l15 == 0) {
#pragma unroll
            for (int r = 0; r < 4; ++r) {
                mlB[wq][0][lg * 4 + r] = mrow[r];
                mlB[wq][1][lg * 4 + r] = lsum[r];
            }
        }
    }
    __syncthreads();
    if (wk == 0) {
        float eA[4], eB[4], rden[4];
#pragma unroll
        for (int r = 0; r < 4; ++r) {
            float mB = mlB[wq][0][lg * 4 + r];
            float lB = mlB[wq][1][lg * 4 + r];
            float ms = fmaxf(mrow[r], mB);
            eA[r] = exp2f((mrow[r] - ms) * L2E);
            eB[r] = exp2f((mB - ms) * L2E);
            rden[r] = 1.0f / (lsum[r] * eA[r] + lB * eB[r]);
        }
#pragma unroll
        for (int jn = 0; jn < 8; ++jn)
#pragma unroll
            for (int r = 0; r < 4; ++r) {
                float ob = oBl[wq][lg * 4 + r][jn * 16 + l15];
                out[((size_t)b * NT + qw0 + lg * 4 + r) * ND + jn * 16 + l15] =
                    (o[jn][r] * eA[r] + ob * eB[r]) * rden[r];
            }
    }
}

extern "C" void kernel_launch(void* const* d_in, const int* in_sizes, int n_in,
                              void* d_out, int out_size, void* d_ws, size_t ws_size,
                              hipStream_t stream) {
    const float* x  = (const float*)d_in[0];
    const float* Wq = (const float*)d_in[1];
    const float* Wk = (const float*)d_in[2];
    const float* Wv = (const float*)d_in[3];
    float* out = (float*)d_out;

    unsigned short* ws  = (unsigned short*)d_ws;
    unsigned short* Wbt = ws;                               // 3*128*1024
    unsigned short* Qb  = Wbt + 3 * ND * NC;                // 8*4096*128
    unsigned short* Kb  = Qb + (size_t)NB * NT * ND;
    unsigned short* Vtb = Kb + (size_t)NB * NT * ND;        // transposed [B][D][T]

    prep_w<<<1536, 256, 0, stream>>>(Wq, Wk, Wv, Wbt);
    qkv_gemm<<<dim3(256, 3), 256, 0, stream>>>(x, Wbt, Qb, Kb, Vtb);
    attn_fwd<<<1024, 256, 0, stream>>>(Qb, Kb, Vtb, out);
}